// Round 16
// baseline (93.365 us; speedup 1.0000x reference)
//
#include <hip/hip_runtime.h>

// Local 8x8 window autocorrelation, stride 4.
// x: (B, C, H, W) fp32 -> out: (B, C, nH, nW, KH, KW) fp32
// out[n, dy, dx] = sum_{i,j} p[i+dy-4][j+dx-4] * p[i][j]  (zero outside window)
//
// R16 = R15 + the occupancy lever ACTUALLY engaged. R15's post-mortem:
// VGPR=68 landed 4 over the 64 boundary (waves/SIMD steps at 64/128/256),
// so the 4-wave split ran at the SAME ~4 waves/SIMD as R12 and only paid
// the split's costs. Here:
//  - __launch_bounds__(256, 8): 2nd arg = min waves/EU -> VGPR cap
//    512/8 = 64 (calibrated on R14: (128,3) -> cap 85, got 84). Roles'
//    live sets are ~42-50 -> shave-4 is remat, not spill.
//    FAILURE SIGNATURE: WRITE_SIZE >> 67.7MB = spill -> revert.
//  - Two-phase 32-window flush (8.3KB LDS, R9/R11/R14-proven byte-exact)
//    so 8 blocks/CU fit LDS (66KB <= 160KB).
//  -> 8 waves/SIMD, 32 waves/CU, 4232 blocks / 2048 resident = 2.07
//    generations: store drain of gen-1 overlaps compute of gen-2.
// Roles (R15, unchanged): W0 d0+d4 (aux reload), W1 d1+c50 (2-ring),
// W2 d2+c60 (3-ring), W3 d3+c70 (4-ring). Numerics & per-cell summation
// order identical to R12/R15 -> absmax unchanged. XCD swizzle 4232=8*529.
// 1KB full-sector wave stores (partial-sector = 3-4.7x: R1/R4 evidence).

constexpr int KH = 8, KW = 8, SH = 4, SW = 4;
constexpr int B = 8, C = 64, H = 96, W = 96;
constexpr int nH = (H - KH) / SH + 1;  // 23
constexpr int nW = (W - KW) / SW + 1;  // 23
constexpr int NWIN = B * C * nH * nW;  // 270848 = 64 * 4232
constexpr int TPB = 256;
constexpr int WPB = 64;                // windows per block
constexpr int HALFW = 32;              // windows staged per flush phase
constexpr int OSTRIDE = 65;            // 64 floats + 1 pad
constexpr int NBLK = NWIN / WPB;       // 4232 = 8 * 529
constexpr int NXCD = 8;
constexpr int CPX = NBLK / NXCD;       // 529

__global__ __launch_bounds__(TPB, 8) void
local_autocorr_kernel(const float* __restrict__ x, float* __restrict__ out) {
    __shared__ float lds[HALFW * OSTRIDE];  // 8320 B

    const int tid  = threadIdx.x;
    const int role = tid >> 6;           // wave index: 0..3 (wave-uniform)
    const int k    = tid & 63;           // window within block

    // Bijective XCD swizzle.
    const int bid = (int)blockIdx.x;
    const int blk = (bid % NXCD) * CPX + bid / NXCD;
    const int n = blk * WPB + k;

    const int w  = n % nW;
    const int tt = n / nW;
    const int h  = tt % nH;
    const int bc = tt / nH;  // b*C + c

    const float* xp = x + ((size_t)bc * H + (size_t)h * SH) * W + (size_t)w * SW;

#define LOADROW(dst, ri)                                                              \
    {                                                                                 \
        const float4 lo_ = *reinterpret_cast<const float4*>(xp + (size_t)(ri)*W);     \
        const float4 hi_ = *reinterpret_cast<const float4*>(xp + (size_t)(ri)*W + 4); \
        dst[0]=lo_.x; dst[1]=lo_.y; dst[2]=lo_.z; dst[3]=lo_.w;                       \
        dst[4]=hi_.x; dst[5]=hi_.y; dst[6]=hi_.z; dst[7]=hi_.w;                       \
    }

    // acc[dx] += A[j+OX] * B[j], static j-guards (48 FMA).
#define FMABLK(ACC, AROW, BROW)                                                       \
    {                                                                                 \
        _Pragma("unroll")                                                             \
        for (int dx = 0; dx < 8; ++dx) {                                              \
            const int OX = dx - 4;                                                    \
            _Pragma("unroll")                                                         \
            for (int j = 0; j < 8; ++j) {                                             \
                if (j + OX < 0 || j + OX >= 8) continue; /* static DCE */             \
                ACC[dx] = fmaf(AROW[j + OX], BROW[j], ACC[dx]);                       \
            }                                                                         \
        }                                                                             \
    }

    // folded cell (4+d, 0): CC += sum_{j=0..3} B[j] * A[j+4]
#define CELLF(CC, AROW, BROW)                                                         \
    {                                                                                 \
        CC = fmaf(BROW[0], AROW[4], CC); CC = fmaf(BROW[1], AROW[5], CC);             \
        CC = fmaf(BROW[2], AROW[6], CC); CC = fmaf(BROW[3], AROW[7], CC);             \
    }

    // Per-role accumulators (kept in role-local scope for min liveness).
    float a0[8], a4[8], a1[8], a2[8], a3[8];
    float c50 = 0.f, c60 = 0.f, c70 = 0.f;

    if (role == 0) {
        // ---- W0: d=0 (dy=4) + d=4 (dy=0). cur + reloaded aux(r-4). ----
#pragma unroll
        for (int dx = 0; dx < 8; ++dx) { a0[dx] = 0.f; a4[dx] = 0.f; }
        float cur[8], aux[8];
#pragma unroll
        for (int r = 0; r < 8; ++r) {
            LOADROW(cur, r)
            FMABLK(a0, cur, cur)                       // d=0: A=B=rows[r]
            if (r >= 4) {
                LOADROW(aux, r - 4)                    // L1/L2-hot (self, 4 steps ago)
                FMABLK(a4, aux, cur)                   // d=4: A=rows[r-4]
            }
            __builtin_amdgcn_sched_barrier(0);
        }
    } else if (role == 1) {
        // ---- W1: d=1 (dy=3) + c50. 2-ring ping-pong. ----
#pragma unroll
        for (int dx = 0; dx < 8; ++dx) a1[dx] = 0.f;
        float rr[2][8];
        LOADROW(rr[0], 0)
#pragma unroll
        for (int r = 1; r < 8; ++r) {
            LOADROW(rr[r & 1], r)
            FMABLK(a1, rr[(r - 1) & 1], rr[r & 1])     // A=rows[r-1], B=rows[r]
            CELLF(c50, rr[(r - 1) & 1], rr[r & 1])
            __builtin_amdgcn_sched_barrier(0);
        }
    } else if (role == 2) {
        // ---- W2: d=2 (dy=2) + c60. 3-ring. ----
#pragma unroll
        for (int dx = 0; dx < 8; ++dx) a2[dx] = 0.f;
        float rr[3][8];
        LOADROW(rr[0], 0)
        LOADROW(rr[1], 1)
#pragma unroll
        for (int r = 2; r < 8; ++r) {
            LOADROW(rr[r % 3], r)                      // overwrites row r-3 (dead)
            FMABLK(a2, rr[(r - 2) % 3], rr[r % 3])     // A=rows[r-2], B=rows[r]
            CELLF(c60, rr[(r - 2) % 3], rr[r % 3])
            __builtin_amdgcn_sched_barrier(0);
        }
    } else {
        // ---- W3: d=3 (dy=1) + c70. 4-ring. ----
#pragma unroll
        for (int dx = 0; dx < 8; ++dx) a3[dx] = 0.f;
        float rr[4][8];
        LOADROW(rr[0], 0)
        LOADROW(rr[1], 1)
        LOADROW(rr[2], 2)
#pragma unroll
        for (int r = 3; r < 8; ++r) {
            LOADROW(rr[r & 3], r)                      // overwrites row r-4 (dead)
            FMABLK(a3, rr[(r - 3) & 3], rr[r & 3])     // A=rows[r-3], B=rows[r]
            CELLF(c70, rr[(r - 3) & 3], rr[r & 3])
            __builtin_amdgcn_sched_barrier(0);
        }
    }
#undef LOADROW
#undef FMABLK
#undef CELLF

    // ---- Two-phase stage + flush (8KB contiguous spans, full-sector). ----
    float* obase = out + (size_t)blk * WPB * 64;
#pragma unroll
    for (int ph = 0; ph < 2; ++ph) {
        if ((k >> 5) == ph) {
            float* slot = &lds[(k & 31) * OSTRIDE];
            if (role == 0) {
                // dy=0 row (a4), dy=4 row (a0)
                *reinterpret_cast<float4*>(slot + 0)  = make_float4(a4[0], a4[1], a4[2], a4[3]);
                *reinterpret_cast<float4*>(slot + 4)  = make_float4(a4[4], a4[5], a4[6], a4[7]);
                *reinterpret_cast<float4*>(slot + 32) = make_float4(a0[0], a0[1], a0[2], a0[3]);
                *reinterpret_cast<float4*>(slot + 36) = make_float4(a0[4], a0[5], a0[6], a0[7]);
            } else if (role == 1) {
                // dy=3 row + mirror row 5 ([5][0]=c50, [5][dx]=a1[8-dx])
                *reinterpret_cast<float4*>(slot + 24) = make_float4(a1[0], a1[1], a1[2], a1[3]);
                *reinterpret_cast<float4*>(slot + 28) = make_float4(a1[4], a1[5], a1[6], a1[7]);
                *reinterpret_cast<float4*>(slot + 40) = make_float4(c50,   a1[7], a1[6], a1[5]);
                *reinterpret_cast<float4*>(slot + 44) = make_float4(a1[4], a1[3], a1[2], a1[1]);
            } else if (role == 2) {
                // dy=2 row + mirror row 6 ([6][0]=c60, [6][dx]=a2[8-dx])
                *reinterpret_cast<float4*>(slot + 16) = make_float4(a2[0], a2[1], a2[2], a2[3]);
                *reinterpret_cast<float4*>(slot + 20) = make_float4(a2[4], a2[5], a2[6], a2[7]);
                *reinterpret_cast<float4*>(slot + 48) = make_float4(c60,   a2[7], a2[6], a2[5]);
                *reinterpret_cast<float4*>(slot + 52) = make_float4(a2[4], a2[3], a2[2], a2[1]);
            } else {
                // dy=1 row + mirror row 7 ([7][0]=c70, [7][dx]=a3[8-dx])
                *reinterpret_cast<float4*>(slot + 8)  = make_float4(a3[0], a3[1], a3[2], a3[3]);
                *reinterpret_cast<float4*>(slot + 12) = make_float4(a3[4], a3[5], a3[6], a3[7]);
                *reinterpret_cast<float4*>(slot + 56) = make_float4(c70,   a3[7], a3[6], a3[5]);
                *reinterpret_cast<float4*>(slot + 60) = make_float4(a3[4], a3[3], a3[2], a3[1]);
            }
        }
        __syncthreads();
        // Flush 32 windows x 16 float4 = 512 slots, 2 per thread; each wave
        // store covers 1KB contiguous (4 complete 256B window regions).
#pragma unroll
        for (int kk = 0; kk < 2; ++kk) {
            const int flat4 = tid + kk * TPB;   // 0..511
            const float4 v = *reinterpret_cast<const float4*>(
                &lds[(flat4 >> 4) * OSTRIDE + (flat4 & 15) * 4]);
            *reinterpret_cast<float4*>(obase + (size_t)ph * HALFW * 64 + flat4 * 4) = v;
        }
        __syncthreads();  // WAR: protect slab before phase 1 restages
    }
}

extern "C" void kernel_launch(void* const* d_in, const int* in_sizes, int n_in,
                              void* d_out, int out_size, void* d_ws, size_t ws_size,
                              hipStream_t stream) {
    const float* x = (const float*)d_in[0];
    float* out = (float*)d_out;

    local_autocorr_kernel<<<NBLK, TPB, 0, stream>>>(x, out);
}

// Round 17
// 33.618 us; speedup vs baseline: 2.7772x; 2.7772x over previous
//
#include <hip/hip_runtime.h>

// Local 8x8 window autocorrelation, stride 4.
// x: (B, C, H, W) fp32 -> out: (B, C, nH, nW, KH, KW) fp32
// out[n, dy, dx] = sum_{i,j} p[i+dy-4][j+dx-4] * p[i][j]  (zero outside window)
//
// R17 = R15 with surgically shaved live sets to cross the 64-VGPR occupancy
// boundary (waves/SIMD steps 8/4/2 at VGPR 64/128/256). Evidence:
//  - R15: VGPR=68 (4 over) -> ran at 4 waves/SIMD like R12 -> 32.7us.
//  - R16: launch_bounds(256,8) forced VGPR=32 -> spill (323MB writes, 93us)
//    but occupancy DID hit 78% -> lever works, forcing mechanism doesn't.
//  - Occupancy curve: ~2/SIMD->90us, 2.3->48, 4->30 across ALL structures;
//    extrapolation to 8/SIMD -> ~18-22us.
// Shave (numerics + summation order identical to R15 -> absmax unchanged):
//  - W3: ring-4 (32 regs) -> cur + aux-reload of row r-3 (16 regs). The row
//    was self-loaded 3 steps earlier -> L1-hot. W3 was the max branch.
//  - W2: ring-3 -> cur + aux-reload of row r-2.
//  - W1 ring-2, W0 cur+aux (unchanged). Max branch ~48 live incl transients.
// NO launch_bounds min-waves arg (R16 lesson). Single-phase 64-window slab
// (16.6KB; 8 blocks/CU = 133KB <= 160KB). Flush = proven 1KB full-sector
// wave stores (partial-sector = 3-4.7x write amp: R1/R4). XCD swizzle
// (4232 = 8*529, bijective). Roles are wave-uniform -> zero divergence.

constexpr int KH = 8, KW = 8, SH = 4, SW = 4;
constexpr int B = 8, C = 64, H = 96, W = 96;
constexpr int nH = (H - KH) / SH + 1;  // 23
constexpr int nW = (W - KW) / SW + 1;  // 23
constexpr int NWIN = B * C * nH * nW;  // 270848 = 64 * 4232
constexpr int TPB = 256;
constexpr int WPB = 64;                // windows per block
constexpr int OSTRIDE = 65;            // 64 floats + 1 pad
constexpr int NBLK = NWIN / WPB;       // 4232 = 8 * 529
constexpr int NXCD = 8;
constexpr int CPX = NBLK / NXCD;       // 529

__global__ __launch_bounds__(TPB) void
local_autocorr_kernel(const float* __restrict__ x, float* __restrict__ out) {
    __shared__ float lds[WPB * OSTRIDE];  // 16640 B

    const int tid  = threadIdx.x;
    const int role = tid >> 6;           // wave index: 0..3 (wave-uniform)
    const int k    = tid & 63;           // window within block

    // Bijective XCD swizzle.
    const int bid = (int)blockIdx.x;
    const int blk = (bid % NXCD) * CPX + bid / NXCD;
    const int n = blk * WPB + k;

    const int w  = n % nW;
    const int tt = n / nW;
    const int h  = tt % nH;
    const int bc = tt / nH;  // b*C + c

    const float* xp = x + ((size_t)bc * H + (size_t)h * SH) * W + (size_t)w * SW;

    float* slot = &lds[k * OSTRIDE];

#define LOADROW(dst, ri)                                                              \
    {                                                                                 \
        const float4 lo_ = *reinterpret_cast<const float4*>(xp + (size_t)(ri)*W);     \
        const float4 hi_ = *reinterpret_cast<const float4*>(xp + (size_t)(ri)*W + 4); \
        dst[0]=lo_.x; dst[1]=lo_.y; dst[2]=lo_.z; dst[3]=lo_.w;                       \
        dst[4]=hi_.x; dst[5]=hi_.y; dst[6]=hi_.z; dst[7]=hi_.w;                       \
    }

    // acc[dx] += A[j+OX] * B[j], static j-guards (48 FMA).
#define FMABLK(ACC, AROW, BROW)                                                       \
    {                                                                                 \
        _Pragma("unroll")                                                             \
        for (int dx = 0; dx < 8; ++dx) {                                              \
            const int OX = dx - 4;                                                    \
            _Pragma("unroll")                                                         \
            for (int j = 0; j < 8; ++j) {                                             \
                if (j + OX < 0 || j + OX >= 8) continue; /* static DCE */             \
                ACC[dx] = fmaf(AROW[j + OX], BROW[j], ACC[dx]);                       \
            }                                                                         \
        }                                                                             \
    }

    // folded cell (4+d, 0): CC += sum_{j=0..3} B[j] * A[j+4]
#define CELLF(CC, AROW, BROW)                                                         \
    {                                                                                 \
        CC = fmaf(BROW[0], AROW[4], CC); CC = fmaf(BROW[1], AROW[5], CC);             \
        CC = fmaf(BROW[2], AROW[6], CC); CC = fmaf(BROW[3], AROW[7], CC);             \
    }

    if (role == 0) {
        // ---- W0: d=0 (dy=4) + d=4 (dy=0). cur + aux-reload(r-4). ~42 live. ----
        float a0[8], a4[8];
#pragma unroll
        for (int dx = 0; dx < 8; ++dx) { a0[dx] = 0.f; a4[dx] = 0.f; }
        float cur[8], aux[8];
#pragma unroll
        for (int r = 0; r < 8; ++r) {
            LOADROW(cur, r)
            FMABLK(a0, cur, cur)                       // d=0: A=B=rows[r]
            if (r >= 4) {
                LOADROW(aux, r - 4)                    // L1-hot (self, 4 steps ago)
                FMABLK(a4, aux, cur)                   // d=4: A=rows[r-4]
            }
            __builtin_amdgcn_sched_barrier(0);
        }
        *reinterpret_cast<float4*>(slot + 0)  = make_float4(a4[0], a4[1], a4[2], a4[3]);
        *reinterpret_cast<float4*>(slot + 4)  = make_float4(a4[4], a4[5], a4[6], a4[7]);
        *reinterpret_cast<float4*>(slot + 32) = make_float4(a0[0], a0[1], a0[2], a0[3]);
        *reinterpret_cast<float4*>(slot + 36) = make_float4(a0[4], a0[5], a0[6], a0[7]);
    } else if (role == 1) {
        // ---- W1: d=1 (dy=3) + c50. 2-ring ping-pong. ~35 live. ----
        float a1[8]; float c50 = 0.f;
#pragma unroll
        for (int dx = 0; dx < 8; ++dx) a1[dx] = 0.f;
        float rr[2][8];
        LOADROW(rr[0], 0)
#pragma unroll
        for (int r = 1; r < 8; ++r) {
            LOADROW(rr[r & 1], r)
            FMABLK(a1, rr[(r - 1) & 1], rr[r & 1])     // A=rows[r-1], B=rows[r]
            CELLF(c50, rr[(r - 1) & 1], rr[r & 1])
            __builtin_amdgcn_sched_barrier(0);
        }
        *reinterpret_cast<float4*>(slot + 24) = make_float4(a1[0], a1[1], a1[2], a1[3]);
        *reinterpret_cast<float4*>(slot + 28) = make_float4(a1[4], a1[5], a1[6], a1[7]);
        *reinterpret_cast<float4*>(slot + 40) = make_float4(c50,   a1[7], a1[6], a1[5]);
        *reinterpret_cast<float4*>(slot + 44) = make_float4(a1[4], a1[3], a1[2], a1[1]);
    } else if (role == 2) {
        // ---- W2: d=2 (dy=2) + c60. cur + aux-reload(r-2). ~35 live. ----
        float a2[8]; float c60 = 0.f;
#pragma unroll
        for (int dx = 0; dx < 8; ++dx) a2[dx] = 0.f;
        float cur[8], aux[8];
#pragma unroll
        for (int r = 2; r < 8; ++r) {
            LOADROW(cur, r)
            LOADROW(aux, r - 2)                        // L1-hot (self, 2 steps ago)
            FMABLK(a2, aux, cur)                       // A=rows[r-2], B=rows[r]
            CELLF(c60, aux, cur)
            __builtin_amdgcn_sched_barrier(0);
        }
        *reinterpret_cast<float4*>(slot + 16) = make_float4(a2[0], a2[1], a2[2], a2[3]);
        *reinterpret_cast<float4*>(slot + 20) = make_float4(a2[4], a2[5], a2[6], a2[7]);
        *reinterpret_cast<float4*>(slot + 48) = make_float4(c60,   a2[7], a2[6], a2[5]);
        *reinterpret_cast<float4*>(slot + 52) = make_float4(a2[4], a2[3], a2[2], a2[1]);
    } else {
        // ---- W3: d=3 (dy=1) + c70. cur + aux-reload(r-3). ~35 live. ----
        float a3[8]; float c70 = 0.f;
#pragma unroll
        for (int dx = 0; dx < 8; ++dx) a3[dx] = 0.f;
        float cur[8], aux[8];
#pragma unroll
        for (int r = 3; r < 8; ++r) {
            LOADROW(cur, r)
            LOADROW(aux, r - 3)                        // L1-hot (self, 3 steps ago)
            FMABLK(a3, aux, cur)                       // A=rows[r-3], B=rows[r]
            CELLF(c70, aux, cur)
            __builtin_amdgcn_sched_barrier(0);
        }
        *reinterpret_cast<float4*>(slot + 8)  = make_float4(a3[0], a3[1], a3[2], a3[3]);
        *reinterpret_cast<float4*>(slot + 12) = make_float4(a3[4], a3[5], a3[6], a3[7]);
        *reinterpret_cast<float4*>(slot + 56) = make_float4(c70,   a3[7], a3[6], a3[5]);
        *reinterpret_cast<float4*>(slot + 60) = make_float4(a3[4], a3[3], a3[2], a3[1]);
    }
#undef LOADROW
#undef FMABLK
#undef CELLF

    __syncthreads();

    // Flush: 64 windows x 16 float4 = 1024 slots, 4 per thread; each wave
    // store instruction covers 1KB contiguous (4 complete 256B regions).
    float* obase = out + (size_t)blk * WPB * 64;
#pragma unroll
    for (int kk = 0; kk < 4; ++kk) {
        const int flat4 = tid + kk * TPB;   // 0..1023
        const float4 v = *reinterpret_cast<const float4*>(
            &lds[(flat4 >> 4) * OSTRIDE + (flat4 & 15) * 4]);
        *reinterpret_cast<float4*>(obase + (size_t)flat4 * 4) = v;
    }
}

extern "C" void kernel_launch(void* const* d_in, const int* in_sizes, int n_in,
                              void* d_out, int out_size, void* d_ws, size_t ws_size,
                              hipStream_t stream) {
    const float* x = (const float*)d_in[0];
    float* out = (float*)d_out;

    local_autocorr_kernel<<<NBLK, TPB, 0, stream>>>(x, out);
}

// Round 18
// 32.409 us; speedup vs baseline: 2.8808x; 1.0373x over previous
//
#include <hip/hip_runtime.h>

// Local 8x8 window autocorrelation, stride 4.
// x: (B, C, H, W) fp32 -> out: (B, C, nH, nW, KH, KW) fp32
// out[n, dy, dx] = sum_{i,j} p[i+dy-4][j+dx-4] * p[i][j]  (zero outside window)
//
// R18 = R17 + __launch_bounds__(256, 4). R17's post-mortem: allocator lands
// at VGPR=68 unconstrained (pads past the ~50-reg live set), 4 over the
// 64-VGPR occupancy boundary (waves/SIMD steps 8/4/2 at 64/128/256).
// CALIBRATED cap model (3 data points): launch_bounds(TPB, w) caps VGPR at
// 256/w, INDEPENDENT of TPB:  (128,4)->64 [R3], (128,3)->84 [R14],
// (256,8)->32 [R16]. R16's spill came from cap 32 << live 50; here cap 64
// sits 4 regs under R17's 68 -> remat, not spill.
// Roles (R15/R17): W0 d0+d4 (cur+aux reload), W1 d1+c50 (2-ring),
// W2 d2+c60 (cur+aux r-2), W3 d3+c70 (cur+aux r-3). All aux reloads are
// self-loaded rows 2-4 steps earlier -> L1-hot. Numerics and per-cell
// summation order identical to R12/R15/R17 -> absmax unchanged (0.0625).
// Single-phase 64-window slab (16.6KB; 8 blocks/CU = 133KB <= 160KB).
// Flush: 1KB full-sector wave stores (partial-sector = 3-4.7x: R1/R4).
// XCD swizzle (4232 = 8*529, bijective). Roles wave-uniform, no divergence.

constexpr int KH = 8, KW = 8, SH = 4, SW = 4;
constexpr int B = 8, C = 64, H = 96, W = 96;
constexpr int nH = (H - KH) / SH + 1;  // 23
constexpr int nW = (W - KW) / SW + 1;  // 23
constexpr int NWIN = B * C * nH * nW;  // 270848 = 64 * 4232
constexpr int TPB = 256;
constexpr int WPB = 64;                // windows per block
constexpr int OSTRIDE = 65;            // 64 floats + 1 pad
constexpr int NBLK = NWIN / WPB;       // 4232 = 8 * 529
constexpr int NXCD = 8;
constexpr int CPX = NBLK / NXCD;       // 529

__global__ __launch_bounds__(TPB, 4) void
local_autocorr_kernel(const float* __restrict__ x, float* __restrict__ out) {
    __shared__ float lds[WPB * OSTRIDE];  // 16640 B

    const int tid  = threadIdx.x;
    const int role = tid >> 6;           // wave index: 0..3 (wave-uniform)
    const int k    = tid & 63;           // window within block

    // Bijective XCD swizzle.
    const int bid = (int)blockIdx.x;
    const int blk = (bid % NXCD) * CPX + bid / NXCD;
    const int n = blk * WPB + k;

    const int w  = n % nW;
    const int tt = n / nW;
    const int h  = tt % nH;
    const int bc = tt / nH;  // b*C + c

    const float* xp = x + ((size_t)bc * H + (size_t)h * SH) * W + (size_t)w * SW;

    float* slot = &lds[k * OSTRIDE];

#define LOADROW(dst, ri)                                                              \
    {                                                                                 \
        const float4 lo_ = *reinterpret_cast<const float4*>(xp + (size_t)(ri)*W);     \
        const float4 hi_ = *reinterpret_cast<const float4*>(xp + (size_t)(ri)*W + 4); \
        dst[0]=lo_.x; dst[1]=lo_.y; dst[2]=lo_.z; dst[3]=lo_.w;                       \
        dst[4]=hi_.x; dst[5]=hi_.y; dst[6]=hi_.z; dst[7]=hi_.w;                       \
    }

    // acc[dx] += A[j+OX] * B[j], static j-guards (48 FMA).
#define FMABLK(ACC, AROW, BROW)                                                       \
    {                                                                                 \
        _Pragma("unroll")                                                             \
        for (int dx = 0; dx < 8; ++dx) {                                              \
            const int OX = dx - 4;                                                    \
            _Pragma("unroll")                                                         \
            for (int j = 0; j < 8; ++j) {                                             \
                if (j + OX < 0 || j + OX >= 8) continue; /* static DCE */             \
                ACC[dx] = fmaf(AROW[j + OX], BROW[j], ACC[dx]);                       \
            }                                                                         \
        }                                                                             \
    }

    // folded cell (4+d, 0): CC += sum_{j=0..3} B[j] * A[j+4]
#define CELLF(CC, AROW, BROW)                                                         \
    {                                                                                 \
        CC = fmaf(BROW[0], AROW[4], CC); CC = fmaf(BROW[1], AROW[5], CC);             \
        CC = fmaf(BROW[2], AROW[6], CC); CC = fmaf(BROW[3], AROW[7], CC);             \
    }

    if (role == 0) {
        // ---- W0: d=0 (dy=4) + d=4 (dy=0). cur + aux-reload(r-4). ----
        float a0[8], a4[8];
#pragma unroll
        for (int dx = 0; dx < 8; ++dx) { a0[dx] = 0.f; a4[dx] = 0.f; }
        float cur[8], aux[8];
#pragma unroll
        for (int r = 0; r < 8; ++r) {
            LOADROW(cur, r)
            FMABLK(a0, cur, cur)                       // d=0: A=B=rows[r]
            if (r >= 4) {
                LOADROW(aux, r - 4)                    // L1-hot (self, 4 steps ago)
                FMABLK(a4, aux, cur)                   // d=4: A=rows[r-4]
            }
            __builtin_amdgcn_sched_barrier(0);
        }
        *reinterpret_cast<float4*>(slot + 0)  = make_float4(a4[0], a4[1], a4[2], a4[3]);
        *reinterpret_cast<float4*>(slot + 4)  = make_float4(a4[4], a4[5], a4[6], a4[7]);
        *reinterpret_cast<float4*>(slot + 32) = make_float4(a0[0], a0[1], a0[2], a0[3]);
        *reinterpret_cast<float4*>(slot + 36) = make_float4(a0[4], a0[5], a0[6], a0[7]);
    } else if (role == 1) {
        // ---- W1: d=1 (dy=3) + c50. 2-ring ping-pong. ----
        float a1[8]; float c50 = 0.f;
#pragma unroll
        for (int dx = 0; dx < 8; ++dx) a1[dx] = 0.f;
        float rr[2][8];
        LOADROW(rr[0], 0)
#pragma unroll
        for (int r = 1; r < 8; ++r) {
            LOADROW(rr[r & 1], r)
            FMABLK(a1, rr[(r - 1) & 1], rr[r & 1])     // A=rows[r-1], B=rows[r]
            CELLF(c50, rr[(r - 1) & 1], rr[r & 1])
            __builtin_amdgcn_sched_barrier(0);
        }
        *reinterpret_cast<float4*>(slot + 24) = make_float4(a1[0], a1[1], a1[2], a1[3]);
        *reinterpret_cast<float4*>(slot + 28) = make_float4(a1[4], a1[5], a1[6], a1[7]);
        *reinterpret_cast<float4*>(slot + 40) = make_float4(c50,   a1[7], a1[6], a1[5]);
        *reinterpret_cast<float4*>(slot + 44) = make_float4(a1[4], a1[3], a1[2], a1[1]);
    } else if (role == 2) {
        // ---- W2: d=2 (dy=2) + c60. cur + aux-reload(r-2). ----
        float a2[8]; float c60 = 0.f;
#pragma unroll
        for (int dx = 0; dx < 8; ++dx) a2[dx] = 0.f;
        float cur[8], aux[8];
#pragma unroll
        for (int r = 2; r < 8; ++r) {
            LOADROW(cur, r)
            LOADROW(aux, r - 2)                        // L1-hot (self, 2 steps ago)
            FMABLK(a2, aux, cur)                       // A=rows[r-2], B=rows[r]
            CELLF(c60, aux, cur)
            __builtin_amdgcn_sched_barrier(0);
        }
        *reinterpret_cast<float4*>(slot + 16) = make_float4(a2[0], a2[1], a2[2], a2[3]);
        *reinterpret_cast<float4*>(slot + 20) = make_float4(a2[4], a2[5], a2[6], a2[7]);
        *reinterpret_cast<float4*>(slot + 48) = make_float4(c60,   a2[7], a2[6], a2[5]);
        *reinterpret_cast<float4*>(slot + 52) = make_float4(a2[4], a2[3], a2[2], a2[1]);
    } else {
        // ---- W3: d=3 (dy=1) + c70. cur + aux-reload(r-3). ----
        float a3[8]; float c70 = 0.f;
#pragma unroll
        for (int dx = 0; dx < 8; ++dx) a3[dx] = 0.f;
        float cur[8], aux[8];
#pragma unroll
        for (int r = 3; r < 8; ++r) {
            LOADROW(cur, r)
            LOADROW(aux, r - 3)                        // L1-hot (self, 3 steps ago)
            FMABLK(a3, aux, cur)                       // A=rows[r-3], B=rows[r]
            CELLF(c70, aux, cur)
            __builtin_amdgcn_sched_barrier(0);
        }
        *reinterpret_cast<float4*>(slot + 8)  = make_float4(a3[0], a3[1], a3[2], a3[3]);
        *reinterpret_cast<float4*>(slot + 12) = make_float4(a3[4], a3[5], a3[6], a3[7]);
        *reinterpret_cast<float4*>(slot + 56) = make_float4(c70,   a3[7], a3[6], a3[5]);
        *reinterpret_cast<float4*>(slot + 60) = make_float4(a3[4], a3[3], a3[2], a3[1]);
    }
#undef LOADROW
#undef FMABLK
#undef CELLF

    __syncthreads();

    // Flush: 64 windows x 16 float4 = 1024 slots, 4 per thread; each wave
    // store instruction covers 1KB contiguous (4 complete 256B regions).
    float* obase = out + (size_t)blk * WPB * 64;
#pragma unroll
    for (int kk = 0; kk < 4; ++kk) {
        const int flat4 = tid + kk * TPB;   // 0..1023
        const float4 v = *reinterpret_cast<const float4*>(
            &lds[(flat4 >> 4) * OSTRIDE + (flat4 & 15) * 4]);
        *reinterpret_cast<float4*>(obase + (size_t)flat4 * 4) = v;
    }
}

extern "C" void kernel_launch(void* const* d_in, const int* in_sizes, int n_in,
                              void* d_out, int out_size, void* d_ws, size_t ws_size,
                              hipStream_t stream) {
    const float* x = (const float*)d_in[0];
    float* out = (float*)d_out;

    local_autocorr_kernel<<<NBLK, TPB, 0, stream>>>(x, out);
}

// Round 19
// 29.663 us; speedup vs baseline: 3.1475x; 1.0926x over previous
//
#include <hip/hip_runtime.h>

// Local 8x8 window autocorrelation, stride 4.
// x: (B, C, H, W) fp32 -> out: (B, C, nH, nW, KH, KW) fp32
// out[n, dy, dx] = sum_{i,j} p[i+dy-4][j+dx-4] * p[i][j]  (zero outside window)
//
// R19 = R12 (best, 29.56us) MINUS the per-step sched_barrier(0).
// Post-mortems R15-R18 closed the occupancy road: the 8-waves/SIMD step
// needs VGPR well under 64 (R16: VGPR=32 -> 78% occ; R18: VGPR=64 -> 28%)
// and the ~68-reg live set can't get there without spilling (R18: +4MB).
// Remaining suspect: sched_barrier(0) pins each r-step's LOADROW->FMABLK
// dependency, exposing ~120-225cyc load latency EVERY step and forbidding
// compiler software-pipelining — the documented anti-pattern (m141: order-
// pinning defeats compiler scheduling; common-mistake #5). Removal is safe
// here because the wave-role split halves the body: worst-case full hoist
// ~110 regs <= the launch_bounds(128,2) cap of 128 (calibrated: cap=256/w).
//   wave 0 (role A): d=0 (dy4), d=1 (dy3) + c50             -> 748 FMA
//   wave 1 (role B): d=2 (dy2), d=3 (dy1), d=4 (dy0) + c60,c70 -> 764 FMA
// Kept: prefetch-2 rows, XCD swizzle (4232 = 8*529, bijective), single-phase
// 64-window LDS slab (16.6KB), 1KB full-sector wave stores (partial-sector
// writes cost 3-4.7x: R1/R4; byte-exact since R6). Summation order per cell
// identical to R12 -> absmax unchanged (0.0625).

constexpr int KH = 8, KW = 8, SH = 4, SW = 4;
constexpr int B = 8, C = 64, H = 96, W = 96;
constexpr int nH = (H - KH) / SH + 1;  // 23
constexpr int nW = (W - KW) / SW + 1;  // 23
constexpr int NWIN = B * C * nH * nW;  // 270848 = 64 * 4232
constexpr int TPB = 128;
constexpr int WPB = 64;                // windows per block
constexpr int OSTRIDE = 65;            // 64 floats + 1 pad
constexpr int NBLK = NWIN / WPB;       // 4232 = 8 * 529
constexpr int NXCD = 8;
constexpr int CPX = NBLK / NXCD;       // 529

__global__ __launch_bounds__(TPB, 2) void
local_autocorr_kernel(const float* __restrict__ x, float* __restrict__ out) {
    __shared__ float lds[WPB * OSTRIDE];  // 16640 B

    const int tid  = threadIdx.x;
    const int role = tid >> 6;           // wave-uniform: wave 0 = A, wave 1 = B
    const int k    = tid & 63;           // window within block

    // Bijective XCD swizzle: blocks bid%8==c form one contiguous span.
    const int bid = (int)blockIdx.x;
    const int blk = (bid % NXCD) * CPX + bid / NXCD;
    const int n = blk * WPB + k;

    const int w  = n % nW;
    const int tt = n / nW;
    const int h  = tt % nH;
    const int bc = tt / nH;  // b*C + c

    const float* xp = x + ((size_t)bc * H + (size_t)h * SH) * W + (size_t)w * SW;

#define LOADROW(dst, ri)                                                              \
    {                                                                                 \
        const float4 lo_ = *reinterpret_cast<const float4*>(xp + (size_t)(ri)*W);     \
        const float4 hi_ = *reinterpret_cast<const float4*>(xp + (size_t)(ri)*W + 4); \
        dst[0]=lo_.x; dst[1]=lo_.y; dst[2]=lo_.z; dst[3]=lo_.w;                       \
        dst[4]=hi_.x; dst[5]=hi_.y; dst[6]=hi_.z; dst[7]=hi_.w;                       \
    }

    float* slot = &lds[k * OSTRIDE];

    if (role == 0) {
        // ---- role A: d=0 (dy=4), d=1 (dy=3), c50. ----
        float accD0[8], accD1[8];
        float c50 = 0.f;
#pragma unroll
        for (int dx = 0; dx < 8; ++dx) { accD0[dx] = 0.f; accD1[dx] = 0.f; }

        float rows[8][8];
        LOADROW(rows[0], 0)
        LOADROW(rows[1], 1)
#pragma unroll
        for (int r = 0; r < 8; ++r) {
            if (r < 6) LOADROW(rows[r + 2], r + 2)
            // d = 0 -> dy = 4
#pragma unroll
            for (int dx = 0; dx < 8; ++dx) {
                const int OX = dx - 4;
#pragma unroll
                for (int j = 0; j < 8; ++j) {
                    if (j + OX < 0 || j + OX >= 8) continue;  // static DCE
                    accD0[dx] = fmaf(rows[r][j + OX], rows[r][j], accD0[dx]);
                }
            }
            // d = 1 -> dy = 3 (+ folded cell (5,0))
            if (r >= 1) {
#pragma unroll
                for (int dx = 0; dx < 8; ++dx) {
                    const int OX = dx - 4;
#pragma unroll
                    for (int j = 0; j < 8; ++j) {
                        if (j + OX < 0 || j + OX >= 8) continue;
                        accD1[dx] = fmaf(rows[r - 1][j + OX], rows[r][j], accD1[dx]);
                    }
                }
                c50 = fmaf(rows[r][0], rows[r - 1][4], c50);
                c50 = fmaf(rows[r][1], rows[r - 1][5], c50);
                c50 = fmaf(rows[r][2], rows[r - 1][6], c50);
                c50 = fmaf(rows[r][3], rows[r - 1][7], c50);
            }
        }

        // Stage rows dy=3,4 + mirror row 5 (out[5][dx] = accD1[8-dx], [5][0]=c50).
        *reinterpret_cast<float4*>(slot + 24) = make_float4(accD1[0], accD1[1], accD1[2], accD1[3]);
        *reinterpret_cast<float4*>(slot + 28) = make_float4(accD1[4], accD1[5], accD1[6], accD1[7]);
        *reinterpret_cast<float4*>(slot + 32) = make_float4(accD0[0], accD0[1], accD0[2], accD0[3]);
        *reinterpret_cast<float4*>(slot + 36) = make_float4(accD0[4], accD0[5], accD0[6], accD0[7]);
        *reinterpret_cast<float4*>(slot + 40) = make_float4(c50,      accD1[7], accD1[6], accD1[5]);
        *reinterpret_cast<float4*>(slot + 44) = make_float4(accD1[4], accD1[3], accD1[2], accD1[1]);
    } else {
        // ---- role B: d=2 (dy=2), d=3 (dy=1), d=4 (dy=0), c60, c70. ----
        float accD2[8], accD3[8], accD4[8];
        float c60 = 0.f, c70 = 0.f;
#pragma unroll
        for (int dx = 0; dx < 8; ++dx) { accD2[dx] = 0.f; accD3[dx] = 0.f; accD4[dx] = 0.f; }

        float rows[8][8];
#pragma unroll
        for (int kk = 0; kk < 4; ++kk) LOADROW(rows[kk], kk)
#pragma unroll
        for (int r = 2; r < 8; ++r) {
            if (r < 6) LOADROW(rows[r + 2], r + 2)
            // d = 2 -> dy = 2 (+ folded cell (6,0))
#pragma unroll
            for (int dx = 0; dx < 8; ++dx) {
                const int OX = dx - 4;
#pragma unroll
                for (int j = 0; j < 8; ++j) {
                    if (j + OX < 0 || j + OX >= 8) continue;
                    accD2[dx] = fmaf(rows[r - 2][j + OX], rows[r][j], accD2[dx]);
                }
            }
            c60 = fmaf(rows[r][0], rows[r - 2][4], c60);
            c60 = fmaf(rows[r][1], rows[r - 2][5], c60);
            c60 = fmaf(rows[r][2], rows[r - 2][6], c60);
            c60 = fmaf(rows[r][3], rows[r - 2][7], c60);
            // d = 3 -> dy = 1 (+ folded cell (7,0))
            if (r >= 3) {
#pragma unroll
                for (int dx = 0; dx < 8; ++dx) {
                    const int OX = dx - 4;
#pragma unroll
                    for (int j = 0; j < 8; ++j) {
                        if (j + OX < 0 || j + OX >= 8) continue;
                        accD3[dx] = fmaf(rows[r - 3][j + OX], rows[r][j], accD3[dx]);
                    }
                }
                c70 = fmaf(rows[r][0], rows[r - 3][4], c70);
                c70 = fmaf(rows[r][1], rows[r - 3][5], c70);
                c70 = fmaf(rows[r][2], rows[r - 3][6], c70);
                c70 = fmaf(rows[r][3], rows[r - 3][7], c70);
            }
            // d = 4 -> dy = 0
            if (r >= 4) {
#pragma unroll
                for (int dx = 0; dx < 8; ++dx) {
                    const int OX = dx - 4;
#pragma unroll
                    for (int j = 0; j < 8; ++j) {
                        if (j + OX < 0 || j + OX >= 8) continue;
                        accD4[dx] = fmaf(rows[r - 4][j + OX], rows[r][j], accD4[dx]);
                    }
                }
            }
        }

        // Stage rows dy=0,1,2 + mirror rows 6,7.
        *reinterpret_cast<float4*>(slot + 0)  = make_float4(accD4[0], accD4[1], accD4[2], accD4[3]);
        *reinterpret_cast<float4*>(slot + 4)  = make_float4(accD4[4], accD4[5], accD4[6], accD4[7]);
        *reinterpret_cast<float4*>(slot + 8)  = make_float4(accD3[0], accD3[1], accD3[2], accD3[3]);
        *reinterpret_cast<float4*>(slot + 12) = make_float4(accD3[4], accD3[5], accD3[6], accD3[7]);
        *reinterpret_cast<float4*>(slot + 16) = make_float4(accD2[0], accD2[1], accD2[2], accD2[3]);
        *reinterpret_cast<float4*>(slot + 20) = make_float4(accD2[4], accD2[5], accD2[6], accD2[7]);
        *reinterpret_cast<float4*>(slot + 48) = make_float4(c60,      accD2[7], accD2[6], accD2[5]);
        *reinterpret_cast<float4*>(slot + 52) = make_float4(accD2[4], accD2[3], accD2[2], accD2[1]);
        *reinterpret_cast<float4*>(slot + 56) = make_float4(c70,      accD3[7], accD3[6], accD3[5]);
        *reinterpret_cast<float4*>(slot + 60) = make_float4(accD3[4], accD3[3], accD3[2], accD3[1]);
    }
#undef LOADROW

    __syncthreads();

    // Flush: 64 windows x 16 float4 = 1024 slots, 8 per thread; each wave
    // store instruction covers 1KB contiguous (4 complete 256B regions).
    float* obase = out + (size_t)blk * WPB * 64;
#pragma unroll
    for (int kk = 0; kk < 8; ++kk) {
        const int flat4 = tid + kk * TPB;   // 0..1023
        const float4 v = *reinterpret_cast<const float4*>(
            &lds[(flat4 >> 4) * OSTRIDE + (flat4 & 15) * 4]);
        *reinterpret_cast<float4*>(obase + (size_t)flat4 * 4) = v;
    }
}

extern "C" void kernel_launch(void* const* d_in, const int* in_sizes, int n_in,
                              void* d_out, int out_size, void* d_ws, size_t ws_size,
                              hipStream_t stream) {
    const float* x = (const float*)d_in[0];
    float* out = (float*)d_out;

    local_autocorr_kernel<<<NBLK, TPB, 0, stream>>>(x, out);
}